// Round 6
// baseline (360.791 us; speedup 1.0000x reference)
//
#include <hip/hip_runtime.h>
#include <math.h>

// Problem constants
#define BATCH 2
#define SEQ   2048
#define NHEAD 16
#define EMB   1024
#define N3E   3072
#define VQL   2016   // SEQ - RESIDUAL_LEN
#define REC_CAP 65536

typedef unsigned short ushort8_t __attribute__((ext_vector_type(8)));
typedef unsigned short ushort4_t __attribute__((ext_vector_type(4)));
typedef short bf16x8 __attribute__((ext_vector_type(8)));
typedef float f32x4 __attribute__((ext_vector_type(4)));
typedef unsigned int uint2_t __attribute__((ext_vector_type(2)));

struct __align__(16) Rec { unsigned dst; unsigned mn_pack; float mn; float scale; };

__device__ __forceinline__ float clipf(float x) {
    return fminf(fmaxf(x, -10000.0f), 10000.0f);
}
__device__ __forceinline__ float bf2f(unsigned short u) {
    return __uint_as_float(((unsigned)u) << 16);
}
__device__ __forceinline__ unsigned short f2bf(float f) {  // round-to-nearest-even
    unsigned u = __float_as_uint(f);
    unsigned r = 0x7FFFu + ((u >> 16) & 1u);
    return (unsigned short)((u + r) >> 16);
}
__device__ __forceinline__ unsigned cvtpk(float lo, float hi) {
    unsigned r;
    asm("v_cvt_pk_bf16_f32 %0, %1, %2" : "=v"(r) : "v"(lo), "v"(hi));
    return r;
}
// async global->LDS, 16B per lane; LDS dest must be wave-uniform base
__device__ __forceinline__ void async_copy16(const unsigned short* g, unsigned short* lds) {
    __builtin_amdgcn_global_load_lds(
        (const __attribute__((address_space(1))) unsigned int*)g,
        (__attribute__((address_space(3))) unsigned int*)lds, 16, 0, 0);
}

// ---------------------------------------------------------------------------
// Pre-split X: fp32 [4096][1024] -> Xh, Xm bf16 (x = hi + mid + eps, eps~2^-18)
// ---------------------------------------------------------------------------
__global__ __launch_bounds__(256) void split_x_kernel(
    const float* __restrict__ X,
    unsigned short* __restrict__ Xh, unsigned short* __restrict__ Xm)
{
    const size_t i8 = ((size_t)blockIdx.x * 256 + threadIdx.x) * 8;
    float4 a = *(const float4*)(X + i8);
    float4 b = *(const float4*)(X + i8 + 4);
    float xs[8] = {a.x, a.y, a.z, a.w, b.x, b.y, b.z, b.w};
    ushort8_t h8, m8;
    #pragma unroll
    for (int j = 0; j < 8; ++j) {
        unsigned short h = f2bf(xs[j]);
        h8[j] = h;
        m8[j] = f2bf(xs[j] - bf2f(h));
    }
    *(ushort8_t*)(Xh + i8) = h8;
    *(ushort8_t*)(Xm + i8) = m8;
}

// ---------------------------------------------------------------------------
// Pre-split + transpose W_qkv: fp32 [1024][3072] -> WTh/WTm/WTl bf16 [3072][1024]
// (3 terms: w = h + m + l + eps, eps ~ 2^-27; GEMM uses h,m; repair uses all 3)
// ---------------------------------------------------------------------------
__global__ __launch_bounds__(256) void split_wt_kernel(
    const float* __restrict__ W,
    unsigned short* __restrict__ WTh, unsigned short* __restrict__ WTm,
    unsigned short* __restrict__ WTl)
{
    __shared__ float t[64][65];
    const int tid = threadIdx.x;
    const int nt = blockIdx.x * 64, kt = blockIdx.y * 64;
    const int r = tid >> 2, cg = (tid & 3) * 16;
    #pragma unroll
    for (int j = 0; j < 4; ++j) {
        float4 v = *(const float4*)(W + (size_t)(kt + r) * N3E + nt + cg + j * 4);
        t[r][cg + j * 4 + 0] = v.x; t[r][cg + j * 4 + 1] = v.y;
        t[r][cg + j * 4 + 2] = v.z; t[r][cg + j * 4 + 3] = v.w;
    }
    __syncthreads();
    ushort8_t h8[2], m8[2], l8[2];
    #pragma unroll
    for (int j = 0; j < 16; ++j) {
        float v = t[cg + j][r];
        unsigned short h = f2bf(v);
        float r1 = v - bf2f(h);
        unsigned short mm = f2bf(r1);
        float r2 = r1 - bf2f(mm);
        h8[j >> 3][j & 7] = h; m8[j >> 3][j & 7] = mm; l8[j >> 3][j & 7] = f2bf(r2);
    }
    size_t off = (size_t)(nt + r) * 1024 + kt + cg;
    *(ushort8_t*)(WTh + off) = h8[0]; *(ushort8_t*)(WTh + off + 8) = h8[1];
    *(ushort8_t*)(WTm + off) = m8[0]; *(ushort8_t*)(WTm + off + 8) = m8[1];
    *(ushort8_t*)(WTl + off) = l8[0]; *(ushort8_t*)(WTl + off + 8) = l8[1];
}

__global__ void zero_cnt_kernel(unsigned* c) {
    if (threadIdx.x == 0 && blockIdx.x == 0) *c = 0;
}

__device__ __forceinline__ void push_flag(unsigned* cnt, Rec* recs, unsigned dst,
                                          int mg, int ng, float mn, float scale) {
    unsigned idx = atomicAdd(cnt, 1u);
    if (idx < REC_CAP) {
        Rec r; r.dst = dst; r.mn_pack = (unsigned)mg | ((unsigned)ng << 12);
        r.mn = mn; r.scale = scale;
        recs[idx] = r;
    }
}

// ---------------------------------------------------------------------------
// QKV GEMM, 3-product split (hh + h*mW + mX*h, err ~2^-18) + KIVI quant
// epilogue with boundary flagging. 128x128 tile, BK=64, 4 waves (2x2 of 64x64),
// global_load_lds staging with granule XOR swizzle on BOTH sides.
// LDS logical As[m][k]: row 128B = 8 granules of 16B; granule swz = gran^(row&7).
// ---------------------------------------------------------------------------
__global__ __launch_bounds__(256) void gemm_qkv3(
    const unsigned short* __restrict__ Xh, const unsigned short* __restrict__ Xm,
    const unsigned short* __restrict__ WTh, const unsigned short* __restrict__ WTm,
    const float* __restrict__ bias,
    unsigned short* __restrict__ Qb, unsigned short* __restrict__ Kb,
    unsigned short* __restrict__ Vt,
    unsigned* __restrict__ cnt, Rec* __restrict__ recs)
{
    __shared__ __align__(16) unsigned short As[128 * 64];
    __shared__ __align__(16) unsigned short Bs[128 * 64];

    const int tid  = threadIdx.x;
    const int wave = tid >> 6, lane = tid & 63, lr = lane & 15, g = lane >> 4;
    const int wr = wave >> 1, wc = wave & 1;
    const int row0 = blockIdx.y * 128, col0 = blockIdx.x * 128;
    const int lr7 = lr & 7;

    // staging lane constants: lane covers (row r0+drow, dest granule lane&7),
    // source granule = dest ^ (row&7) = (lane&7) ^ drow  (r0 multiple of 8)
    const int drow = lane >> 3;
    const int swz8 = ((lane & 7) ^ drow) * 8;   // ushort offset of source granule
    const int arow0 = wave * 32;                // wave's staging row block

    const unsigned short* Aseg[3] = {Xh, Xh, Xm};
    const unsigned short* Bseg[3] = {WTh, WTm, WTh};

    f32x4 acc[4][4] = {};

    for (int seg = 0; seg < 3; ++seg) {
        const unsigned short* ApL = Aseg[seg] + (size_t)(row0 + arow0 + drow) * 1024 + swz8;
        const unsigned short* BpL = Bseg[seg] + (size_t)(col0 + arow0 + drow) * 1024 + swz8;
        for (int tt = 0; tt < 16; ++tt) {
            __syncthreads();   // previous tile fully consumed
            #pragma unroll
            for (int c = 0; c < 4; ++c) {
                async_copy16(ApL + (size_t)(c * 8) * 1024 + tt * 64, &As[(arow0 + c * 8) * 64]);
                async_copy16(BpL + (size_t)(c * 8) * 1024 + tt * 64, &Bs[(arow0 + c * 8) * 64]);
            }
            __syncthreads();   // compiler drains vmcnt(0) before s_barrier

            #pragma unroll
            for (int h = 0; h < 2; ++h) {
                const int gr = ((h * 4 + g) ^ lr7) * 8;   // swizzled read granule
                bf16x8 a[4], b[4];
                #pragma unroll
                for (int mf = 0; mf < 4; ++mf)
                    a[mf] = *(const bf16x8*)&As[(wr * 64 + mf * 16 + lr) * 64 + gr];
                #pragma unroll
                for (int nf = 0; nf < 4; ++nf)
                    b[nf] = *(const bf16x8*)&Bs[(wc * 64 + nf * 16 + lr) * 64 + gr];
                #pragma unroll
                for (int nf = 0; nf < 4; ++nf)
                    #pragma unroll
                    for (int mf = 0; mf < 4; ++mf)
                        acc[mf][nf] = __builtin_amdgcn_mfma_f32_16x16x32_bf16(
                            a[mf], b[nf], acc[mf][nf], 0, 0, 0);
            }
        }
    }

    // ================= epilogue =================
    // C frag: row = wr*64+m*16+g*4+r, col = wc*64+n*16+lr
    const int which = col0 >> 10;
    const int hcol  = ((col0 + wc * 64) & 1023) >> 6;
    const int b     = row0 >> 11;
    const int s_base = (row0 & 2047) + wr * 64;

    float bo[4];
    #pragma unroll
    for (int n = 0; n < 4; ++n) bo[n] = bias[col0 + wc * 64 + n * 16 + lr];
    #pragma unroll
    for (int m = 0; m < 4; ++m)
        #pragma unroll
        for (int n = 0; n < 4; ++n)
            #pragma unroll
            for (int r = 0; r < 4; ++r)
                acc[m][n][r] += bo[n];

    if (which == 0) {
        unsigned short* qdst = Qb + (((size_t)b * NHEAD + hcol) * SEQ) * 64;
        #pragma unroll
        for (int m = 0; m < 4; ++m)
            #pragma unroll
            for (int r = 0; r < 4; ++r) {
                int s = s_base + m * 16 + g * 4 + r;
                #pragma unroll
                for (int n = 0; n < 4; ++n)
                    qdst[(size_t)s * 64 + n * 16 + lr] = f2bf(acc[m][n][r]);
            }
    } else if (which == 1) {
        // key quant: per-channel min/max over this wave's 64 tokens
        #pragma unroll
        for (int n = 0; n < 4; ++n) {
            float cmn = INFINITY, cmx = -INFINITY;
            #pragma unroll
            for (int m = 0; m < 4; ++m)
                #pragma unroll
                for (int r = 0; r < 4; ++r) {
                    float v = clipf(acc[m][n][r]);
                    acc[m][n][r] = v;
                    cmn = fminf(cmn, v); cmx = fmaxf(cmx, v);
                }
            cmn = fminf(cmn, __shfl_xor(cmn, 16)); cmx = fmaxf(cmx, __shfl_xor(cmx, 16));
            cmn = fminf(cmn, __shfl_xor(cmn, 32)); cmx = fmaxf(cmx, __shfl_xor(cmx, 32));
            float scale = fmaxf((cmx - cmn) / 3.0f, 1e-8f);
            float tol = 0.5f - 1e-3f / scale;
            #pragma unroll
            for (int m = 0; m < 4; ++m)
                #pragma unroll
                for (int r = 0; r < 4; ++r) {
                    float f = (acc[m][n][r] - cmn) / scale;
                    float qv = rintf(f);
                    if (fabsf(f - qv) > tol) {
                        int s  = s_base + m * 16 + g * 4 + r;
                        int mg = row0 + wr * 64 + m * 16 + g * 4 + r;
                        int ng = col0 + wc * 64 + n * 16 + lr;
                        unsigned dst = 4194304u +
                            (unsigned)(((b * NHEAD + hcol) * SEQ + s) * 64 + n * 16 + lr);
                        push_flag(cnt, recs, dst, mg, ng, cmn, scale);
                    }
                    acc[m][n][r] = qv * scale + cmn;
                }
        }
        unsigned short* kdst = Kb + (((size_t)b * NHEAD + hcol) * SEQ) * 64;
        #pragma unroll
        for (int m = 0; m < 4; ++m)
            #pragma unroll
            for (int r = 0; r < 4; ++r) {
                int s = s_base + m * 16 + g * 4 + r;
                #pragma unroll
                for (int n = 0; n < 4; ++n)
                    kdst[(size_t)s * 64 + n * 16 + lr] = f2bf(acc[m][n][r]);
            }
    } else {
        // value quant: per-token min/max over 64 channels; s < VQL only
        #pragma unroll
        for (int m = 0; m < 4; ++m)
            #pragma unroll
            for (int r = 0; r < 4; ++r) {
                float c[4];
                #pragma unroll
                for (int n = 0; n < 4; ++n) c[n] = clipf(acc[m][n][r]);
                float mn = fminf(fminf(c[0], c[1]), fminf(c[2], c[3]));
                float mx = fmaxf(fmaxf(c[0], c[1]), fmaxf(c[2], c[3]));
                #pragma unroll
                for (int msk = 1; msk < 16; msk <<= 1) {
                    mn = fminf(mn, __shfl_xor(mn, msk));
                    mx = fmaxf(mx, __shfl_xor(mx, msk));
                }
                int s = s_base + m * 16 + g * 4 + r;
                if (s < VQL) {
                    float scale = fmaxf((mx - mn) / 3.0f, 1e-8f);
                    float tol = 0.5f - 1e-3f / scale;
                    #pragma unroll
                    for (int n = 0; n < 4; ++n) {
                        float f = (c[n] - mn) / scale;
                        float qv = rintf(f);
                        if (fabsf(f - qv) > tol) {
                            int mg = row0 + wr * 64 + m * 16 + g * 4 + r;
                            int ng = col0 + wc * 64 + n * 16 + lr;
                            unsigned dst = 8388608u +
                                (unsigned)((((b * NHEAD + hcol) * 64) + n * 16 + lr) * SEQ + s);
                            push_flag(cnt, recs, dst, mg, ng, mn, scale);
                        }
                        acc[m][n][r] = qv * scale + mn;
                    }
                }
                // else raw unclipped tail (acc keeps bias-added value)
            }
        #pragma unroll
        for (int m = 0; m < 4; ++m)
            #pragma unroll
            for (int n = 0; n < 4; ++n) {
                ushort4_t o;
                #pragma unroll
                for (int r = 0; r < 4; ++r) o[r] = f2bf(acc[m][n][r]);
                *(ushort4_t*)(Vt + ((((size_t)b * NHEAD + hcol) * 64) + n * 16 + lr) * SEQ
                                 + s_base + m * 16 + g * 4) = o;
            }
    }
}

// ---------------------------------------------------------------------------
// Boundary repair: one wave per record; exact fp32 dot (X fp32 x W from 3-term
// bf16 split, eps~2^-27), requantize with the SAME group's mn/scale, rewrite
// the single bf16 element. Order-independent -> deterministic output.
// ---------------------------------------------------------------------------
__global__ __launch_bounds__(256) void repair_kernel(
    const float* __restrict__ X,
    const unsigned short* __restrict__ WTh, const unsigned short* __restrict__ WTm,
    const unsigned short* __restrict__ WTl,
    const float* __restrict__ bias, unsigned short* __restrict__ wsu,
    const unsigned* __restrict__ cnt, const Rec* __restrict__ recs)
{
    const int lane = threadIdx.x & 63;
    const int wid  = blockIdx.x * 4 + (threadIdx.x >> 6);
    unsigned nrec = *cnt; if (nrec > REC_CAP) nrec = REC_CAP;
    for (unsigned i = wid; i < nrec; i += gridDim.x * 4) {
        Rec rc = recs[i];
        int mg = rc.mn_pack & 4095;
        int ng = (rc.mn_pack >> 12) & 4095;
        const float* xr          = X   + (size_t)mg * 1024 + lane * 16;
        const unsigned short* wh = WTh + (size_t)ng * 1024 + lane * 16;
        const unsigned short* wm = WTm + (size_t)ng * 1024 + lane * 16;
        const unsigned short* wl = WTl + (size_t)ng * 1024 + lane * 16;
        float s = 0.f;
        #pragma unroll
        for (int j4 = 0; j4 < 4; ++j4) {
            float4 xv = *(const float4*)(xr + j4 * 4);
            float xs[4] = {xv.x, xv.y, xv.z, xv.w};
            #pragma unroll
            for (int e = 0; e < 4; ++e) {
                int j = j4 * 4 + e;
                s += xs[e] * (bf2f(wh[j]) + bf2f(wm[j]) + bf2f(wl[j]));
            }
        }
        #pragma unroll
        for (int msk = 1; msk < 64; msk <<= 1) s += __shfl_xor(s, msk);
        if (lane == 0) {
            float v = clipf(s + bias[ng]);
            float val = rintf((v - rc.mn) / rc.scale) * rc.scale + rc.mn;
            wsu[rc.dst] = f2bf(val);
        }
    }
}

// ---------------------------------------------------------------------------
// MFMA flash attention (bf16, fp32 accum), causal, scale 1/8. (unchanged)
// Q bf16 [B,H,S,D] (y overwrites it), K bf16 [B,H,S,D], V bf16 [B,H,D,S].
// ---------------------------------------------------------------------------
__global__ __launch_bounds__(256) void attn_mfma(
    unsigned short* __restrict__ QY,
    const unsigned short* __restrict__ K,
    const unsigned short* __restrict__ Vt)
{
    __shared__ unsigned short Ks [64][72];
    __shared__ unsigned short VsT[64][72];
    __shared__ unsigned short Ps [4][16][72];

    const int tid  = threadIdx.x;
    const int wave = tid >> 6;
    const int lane = tid & 63;
    const int lr   = lane & 15;
    const int g    = lane >> 4;

    const int bid = blockIdx.x;
    const int qt  = 31 - (bid >> 5);
    const int bh  = bid & 31;
    const size_t base = (size_t)bh * (SEQ * 64);

    const int qrow = qt * 64 + wave * 16 + lr;
    const unsigned short* qp = QY + base + (size_t)qrow * 64;
    bf16x8 aq[2];
    #pragma unroll
    for (int ka = 0; ka < 2; ++ka)
        aq[ka] = *(const bf16x8*)(qp + ka * 32 + g * 8);

    f32x4 o[4] = {};
    float m[4]    = {-1e30f, -1e30f, -1e30f, -1e30f};
    float lsum[4] = {};
    const float sc = 0.125f;

    const int str = tid >> 2;
    const int stc = (tid & 3) << 4;

    for (int jt = 0; jt <= qt; ++jt) {
        __syncthreads();
        {
            const unsigned short* kg = K + base + ((size_t)(jt * 64 + str) << 6) + stc;
            *(ushort8_t*)&Ks[str][stc]     = *(const ushort8_t*)kg;
            *(ushort8_t*)&Ks[str][stc + 8] = *(const ushort8_t*)(kg + 8);
            const unsigned short* vg = Vt + base + ((size_t)str << 11) + jt * 64 + stc;
            *(ushort8_t*)&VsT[str][stc]     = *(const ushort8_t*)vg;
            *(ushort8_t*)&VsT[str][stc + 8] = *(const ushort8_t*)(vg + 8);
        }
        __syncthreads();

        f32x4 s[4] = {};
        #pragma unroll
        for (int f = 0; f < 4; ++f) {
            #pragma unroll
            for (int ka = 0; ka < 2; ++ka) {
                bf16x8 bk = *(const bf16x8*)&Ks[f * 16 + lr][ka * 32 + g * 8];
                s[f] = __builtin_amdgcn_mfma_f32_16x16x32_bf16(aq[ka], bk, s[f], 0, 0, 0);
            }
        }

        const bool diag = (jt == qt);
        float mx[4];
        #pragma unroll
        for (int r = 0; r < 4; ++r) {
            const int ql = wave * 16 + g * 4 + r;
            float vmax = -1e30f;
            #pragma unroll
            for (int f = 0; f < 4; ++f) {
                float v = s[f][r] * sc;
                if (diag && (f * 16 + lr) > ql) v = -1e30f;
                s[f][r] = v;
                vmax = fmaxf(vmax, v);
            }
            mx[r] = vmax;
        }
        #pragma unroll
        for (int msk = 1; msk < 16; msk <<= 1)
            #pragma unroll
            for (int r = 0; r < 4; ++r)
                mx[r] = fmaxf(mx[r], __shfl_xor(mx[r], msk));

        float alpha[4], tsum[4];
        #pragma unroll
        for (int r = 0; r < 4; ++r) {
            float mn = fmaxf(m[r], mx[r]);
            alpha[r] = __expf(m[r] - mn);
            m[r] = mn;
            float ts = 0.0f;
            #pragma unroll
            for (int f = 0; f < 4; ++f) {
                float p = __expf(s[f][r] - mn);
                unsigned short ub = f2bf(p);
                Ps[wave][g * 4 + r][f * 16 + lr] = ub;
                ts += bf2f(ub);
            }
            tsum[r] = ts;
        }
        #pragma unroll
        for (int msk = 1; msk < 16; msk <<= 1)
            #pragma unroll
            for (int r = 0; r < 4; ++r)
                tsum[r] += __shfl_xor(tsum[r], msk);
        #pragma unroll
        for (int r = 0; r < 4; ++r) {
            lsum[r] = lsum[r] * alpha[r] + tsum[r];
            #pragma unroll
            for (int df = 0; df < 4; ++df) o[df][r] *= alpha[r];
        }

        asm volatile("s_waitcnt lgkmcnt(0)" ::: "memory");
        __builtin_amdgcn_sched_barrier(0);

        bf16x8 pa[2];
        #pragma unroll
        for (int kb = 0; kb < 2; ++kb)
            pa[kb] = *(const bf16x8*)&Ps[wave][lr][kb * 32 + g * 8];
        #pragma unroll
        for (int df = 0; df < 4; ++df) {
            #pragma unroll
            for (int kb = 0; kb < 2; ++kb) {
                bf16x8 vb = *(const bf16x8*)&VsT[df * 16 + lr][kb * 32 + g * 8];
                o[df] = __builtin_amdgcn_mfma_f32_16x16x32_bf16(pa[kb], vb, o[df], 0, 0, 0);
            }
        }
    }

    float invl[4];
    #pragma unroll
    for (int r = 0; r < 4; ++r) invl[r] = 1.0f / lsum[r];
    #pragma unroll
    for (int df = 0; df < 4; ++df)
        #pragma unroll
        for (int r = 0; r < 4; ++r) {
            int q = qt * 64 + wave * 16 + g * 4 + r;
            QY[base + (size_t)q * 64 + df * 16 + lr] = f2bf(o[df][r] * invl[r]);
        }
}

// ---------------------------------------------------------------------------
// Proj GEMM via bf16 MFMA (unchanged from round 5).
// ---------------------------------------------------------------------------
#define PJ_PAD 72
__global__ __launch_bounds__(256, 2) void gemm_proj_mfma(
    const unsigned short* __restrict__ Y, const float* __restrict__ W,
    const float* __restrict__ bias, float* __restrict__ C)
{
    __shared__ unsigned short A2[2][128][PJ_PAD];
    __shared__ unsigned short B2[2][128][PJ_PAD];

    const int tid  = threadIdx.x;
    const int wave = tid >> 6, lane = tid & 63, lr = lane & 15, g = lane >> 4;
    const int wr = wave >> 1, wc = wave & 1;
    const int row0 = blockIdx.y * 128, col0 = blockIdx.x * 128;
    const int b = row0 >> 11, s0 = row0 & 2047;

    const int ra  = tid >> 1,       ca  = (tid & 1) * 32;
    const int cb4 = (tid & 31) * 4, kb4 = (tid >> 5) * 4;

    ushort8_t a_reg[4];
    float bw[2][4][4];

    {
        const unsigned short* gy = Y + ((((size_t)b * NHEAD + 0) * SEQ + s0 + ra) << 6) + ca;
        #pragma unroll
        for (int i = 0; i < 4; ++i) a_reg[i] = *(const ushort8_t*)(gy + i * 8);
        const float* gw = W + (size_t)kb4 * EMB + col0 + cb4;
        #pragma unroll
        for (int half = 0; half < 2; ++half)
            #pragma unroll
            for (int i = 0; i < 4; ++i)
                *(float4*)bw[half][i] = *(const float4*)(gw + (size_t)(half * 32 + i) * EMB);
        #pragma unroll
        for (int i = 0; i < 4; ++i) *(ushort8_t*)&A2[0][ra][ca + i * 8] = a_reg[i];
        #pragma unroll
        for (int half = 0; half < 2; ++half)
            #pragma unroll
            for (int j = 0; j < 4; ++j) {
                unsigned w2[2];
                w2[0] = cvtpk(bw[half][0][j], bw[half][1][j]);
                w2[1] = cvtpk(bw[half][2][j], bw[half][3][j]);
                *(uint2_t*)&B2[0][cb4 + j][half * 32 + kb4] = *(uint2_t*)w2;
            }
    }
    __syncthreads();

    f32x4 acc[4][4] = {};

    for (int t = 0; t < 16; ++t) {
        const int cur = t & 1;
        if (t < 15) {
            const unsigned short* gy =
                Y + ((((size_t)b * NHEAD + (t + 1)) * SEQ + s0 + ra) << 6) + ca;
            #pragma unroll
            for (int i = 0; i < 4; ++i) a_reg[i] = *(const ushort8_t*)(gy + i * 8);
            const float* gw = W + (size_t)((t + 1) * 64 + kb4) * EMB + col0 + cb4;
            #pragma unroll
            for (int half = 0; half < 2; ++half)
                #pragma unroll
                for (int i = 0; i < 4; ++i)
                    *(float4*)bw[half][i] = *(const float4*)(gw + (size_t)(half * 32 + i) * EMB);
        }
        #pragma unroll
        for (int kk = 0; kk < 2; ++kk) {
            bf16x8 af[4];
            #pragma unroll
            for (int m = 0; m < 4; ++m)
                af[m] = *(const bf16x8*)&A2[cur][wr * 64 + m * 16 + lr][kk * 32 + g * 8];
            #pragma unroll
            for (int n = 0; n < 4; ++n) {
                bf16x8 bf = *(const bf16x8*)&B2[cur][wc * 64 + n * 16 + lr][kk * 32 + g * 8];
                #pragma unroll
                for (int m = 0; m < 4; ++m)
                    acc[m][n] = __builtin_amdgcn_mfma_f32_16x16x32_bf16(af[m], bf, acc[m][n], 0, 0, 0);
            }
        }
        if (t < 15) {
            const int nxt = cur ^ 1;
            #pragma unroll
            for (int i = 0; i < 4; ++i) *(ushort8_t*)&A2[nxt][ra][ca + i * 8] = a_reg[i];
            #pragma unroll
            for (int half = 0; half < 2; ++half)
                #pragma unroll
                for (int j = 0; j < 4; ++j) {
                    unsigned w2[2];
                    w2[0] = cvtpk(bw[half][0][j], bw[half][1][j]);
                    w2[1] = cvtpk(bw[half][2][j], bw[half][3][j]);
                    *(uint2_t*)&B2[nxt][cb4 + j][half * 32 + kb4] = *(uint2_t*)w2;
                }
        }
        __syncthreads();
    }

    float bo[4];
    #pragma unroll
    for (int n = 0; n < 4; ++n) bo[n] = bias[col0 + wc * 64 + n * 16 + lr];
    #pragma unroll
    for (int m = 0; m < 4; ++m)
        #pragma unroll
        for (int r = 0; r < 4; ++r) {
            int mrow = row0 + wr * 64 + m * 16 + g * 4 + r;
            #pragma unroll
            for (int n = 0; n < 4; ++n)
                C[(size_t)mrow * EMB + col0 + wc * 64 + n * 16 + lr] = acc[m][n][r] + bo[n];
        }
}

// ---------------------------------------------------------------------------
extern "C" void kernel_launch(void* const* d_in, const int* in_sizes, int n_in,
                              void* d_out, int out_size, void* d_ws, size_t ws_size,
                              hipStream_t stream)
{
    const float* x     = (const float*)d_in[0];
    const float* Wqkv  = (const float*)d_in[1];
    const float* bqkv  = (const float*)d_in[2];
    const float* Wproj = (const float*)d_in[3];
    const float* bproj = (const float*)d_in[4];
    float* out = (float*)d_out;

    // Workspace layout (59.2 MiB total):
    //  [0,8)    MiB q bf16 [B,H,S,D] (y overwrites)
    //  [8,16)   MiB k bf16 [B,H,S,D]
    //  [16,24)  MiB v bf16 [B,H,D,S]
    //  [24,32)  MiB Xh   [32,40) Xm        bf16 [4096][1024]
    //  [40,46)  MiB WTh  [46,52) WTm  [52,58) WTl  bf16 [3072][1024]
    //  [58 MiB) counter + records
    char* ws = (char*)d_ws;
    unsigned short* q   = (unsigned short*)ws;
    unsigned short* kb  = (unsigned short*)(ws + (8u  << 20));
    unsigned short* vt  = (unsigned short*)(ws + (16u << 20));
    unsigned short* Xh  = (unsigned short*)(ws + (24u << 20));
    unsigned short* Xm  = (unsigned short*)(ws + (32u << 20));
    unsigned short* WTh = (unsigned short*)(ws + (40u << 20));
    unsigned short* WTm = (unsigned short*)(ws + (46u << 20));
    unsigned short* WTl = (unsigned short*)(ws + (52u << 20));
    unsigned*       cnt = (unsigned*)(ws + (58u << 20));
    Rec*           recs = (Rec*)(ws + (58u << 20) + 256);

    zero_cnt_kernel<<<1, 64, 0, stream>>>(cnt);
    split_x_kernel<<<2048, 256, 0, stream>>>(x, Xh, Xm);
    split_wt_kernel<<<dim3(48, 16), 256, 0, stream>>>(Wqkv, WTh, WTm, WTl);
    gemm_qkv3<<<dim3(N3E / 128, 4096 / 128), 256, 0, stream>>>(
        Xh, Xm, WTh, WTm, bqkv, q, kb, vt, cnt, recs);
    repair_kernel<<<128, 256, 0, stream>>>(x, WTh, WTm, WTl, bqkv,
                                           (unsigned short*)d_ws, cnt, recs);
    attn_mfma<<<dim3(32 * 32), 256, 0, stream>>>(q, kb, vt);
    gemm_proj_mfma<<<dim3(EMB / 128, 4096 / 128), 256, 0, stream>>>(q, Wproj, bproj, out);
}

// Round 7
// 342.772 us; speedup vs baseline: 1.0526x; 1.0526x over previous
//
#include <hip/hip_runtime.h>
#include <math.h>

// Problem constants
#define BATCH 2
#define SEQ   2048
#define NHEAD 16
#define EMB   1024
#define N3E   3072
#define VQL   2016   // SEQ - RESIDUAL_LEN
#define REC_CAP 65536

typedef unsigned short ushort8_t __attribute__((ext_vector_type(8)));
typedef unsigned short ushort4_t __attribute__((ext_vector_type(4)));
typedef short bf16x8 __attribute__((ext_vector_type(8)));
typedef float f32x4 __attribute__((ext_vector_type(4)));
typedef unsigned int uint2_t __attribute__((ext_vector_type(2)));

struct __align__(16) Rec { unsigned dst; unsigned mn_pack; float mn; float scale; };

__device__ __forceinline__ float clipf(float x) {
    return fminf(fmaxf(x, -10000.0f), 10000.0f);
}
__device__ __forceinline__ float bf2f(unsigned short u) {
    return __uint_as_float(((unsigned)u) << 16);
}
__device__ __forceinline__ unsigned short f2bf(float f) {  // round-to-nearest-even
    unsigned u = __float_as_uint(f);
    unsigned r = 0x7FFFu + ((u >> 16) & 1u);
    return (unsigned short)((u + r) >> 16);
}
__device__ __forceinline__ unsigned cvtpk(float lo, float hi) {
    unsigned r;
    asm("v_cvt_pk_bf16_f32 %0, %1, %2" : "=v"(r) : "v"(lo), "v"(hi));
    return r;
}
// async global->LDS, 16B per lane; LDS dest must be wave-uniform base
__device__ __forceinline__ void async_copy16(const unsigned short* g, unsigned short* lds) {
    __builtin_amdgcn_global_load_lds(
        (const __attribute__((address_space(1))) unsigned int*)g,
        (__attribute__((address_space(3))) unsigned int*)lds, 16, 0, 0);
}

// ---------------------------------------------------------------------------
// Pre-split X: fp32 [4096][1024] -> Xh, Xm bf16 (x = hi + mid + eps, eps~2^-18)
// ---------------------------------------------------------------------------
__global__ __launch_bounds__(256) void split_x_kernel(
    const float* __restrict__ X,
    unsigned short* __restrict__ Xh, unsigned short* __restrict__ Xm)
{
    const size_t i8 = ((size_t)blockIdx.x * 256 + threadIdx.x) * 8;
    float4 a = *(const float4*)(X + i8);
    float4 b = *(const float4*)(X + i8 + 4);
    float xs[8] = {a.x, a.y, a.z, a.w, b.x, b.y, b.z, b.w};
    ushort8_t h8, m8;
    #pragma unroll
    for (int j = 0; j < 8; ++j) {
        unsigned short h = f2bf(xs[j]);
        h8[j] = h;
        m8[j] = f2bf(xs[j] - bf2f(h));
    }
    *(ushort8_t*)(Xh + i8) = h8;
    *(ushort8_t*)(Xm + i8) = m8;
}

// ---------------------------------------------------------------------------
// Pre-split + transpose W_qkv: fp32 [1024][3072] -> WTh/WTm/WTl bf16 [3072][1024]
// ---------------------------------------------------------------------------
__global__ __launch_bounds__(256) void split_wt_kernel(
    const float* __restrict__ W,
    unsigned short* __restrict__ WTh, unsigned short* __restrict__ WTm,
    unsigned short* __restrict__ WTl)
{
    __shared__ float t[64][65];
    const int tid = threadIdx.x;
    const int nt = blockIdx.x * 64, kt = blockIdx.y * 64;
    const int r = tid >> 2, cg = (tid & 3) * 16;
    #pragma unroll
    for (int j = 0; j < 4; ++j) {
        float4 v = *(const float4*)(W + (size_t)(kt + r) * N3E + nt + cg + j * 4);
        t[r][cg + j * 4 + 0] = v.x; t[r][cg + j * 4 + 1] = v.y;
        t[r][cg + j * 4 + 2] = v.z; t[r][cg + j * 4 + 3] = v.w;
    }
    __syncthreads();
    ushort8_t h8[2], m8[2], l8[2];
    #pragma unroll
    for (int j = 0; j < 16; ++j) {
        float v = t[cg + j][r];
        unsigned short h = f2bf(v);
        float r1 = v - bf2f(h);
        unsigned short mm = f2bf(r1);
        float r2 = r1 - bf2f(mm);
        h8[j >> 3][j & 7] = h; m8[j >> 3][j & 7] = mm; l8[j >> 3][j & 7] = f2bf(r2);
    }
    size_t off = (size_t)(nt + r) * 1024 + kt + cg;
    *(ushort8_t*)(WTh + off) = h8[0]; *(ushort8_t*)(WTh + off + 8) = h8[1];
    *(ushort8_t*)(WTm + off) = m8[0]; *(ushort8_t*)(WTm + off + 8) = m8[1];
    *(ushort8_t*)(WTl + off) = l8[0]; *(ushort8_t*)(WTl + off + 8) = l8[1];
}

__global__ void zero_cnt_kernel(unsigned* c) {
    if (threadIdx.x == 0 && blockIdx.x == 0) *c = 0;
}

__device__ __forceinline__ void push_flag(unsigned* cnt, Rec* recs, unsigned dst,
                                          int mg, int ng, float mn, float scale) {
    unsigned idx = atomicAdd(cnt, 1u);
    if (idx < REC_CAP) {
        Rec r; r.dst = dst; r.mn_pack = (unsigned)mg | ((unsigned)ng << 12);
        r.mn = mn; r.scale = scale;
        recs[idx] = r;
    }
}

// ---------------------------------------------------------------------------
// QKV GEMM, fused 3-product split (XhWh + XhWm + XmWh, err ~2^-18), KIVI quant
// epilogue with boundary flagging. 128x128 tile, BK=32, 4 waves (2x2 of 64x64).
// DOUBLE-BUFFERED global_load_lds pipeline (T3-minimum): stage tile t+1, then
// compute tile t, then __syncthreads() (vmcnt(0) drain) -- loads fly under MFMA.
// LDS tile row = 32 ushorts (64B) = 4 granules of 16B; granule XOR key
// (row>>1)&3 applied on the global SOURCE (linear DMA dest) and on ds_read.
// ---------------------------------------------------------------------------
__global__ __launch_bounds__(256, 2) void gemm_qkv3(
    const unsigned short* __restrict__ Xh, const unsigned short* __restrict__ Xm,
    const unsigned short* __restrict__ WTh, const unsigned short* __restrict__ WTm,
    const float* __restrict__ bias,
    unsigned short* __restrict__ Qb, unsigned short* __restrict__ Kb,
    unsigned short* __restrict__ Vt,
    unsigned* __restrict__ cnt, Rec* __restrict__ recs)
{
    // [buf][tile: 0=XhA 1=XmA 2=WhB 3=WmB][128 rows * 32 cols]
    __shared__ __align__(16) unsigned short LDS[2][4][128 * 32];

    const int tid  = threadIdx.x;
    const int wave = tid >> 6, lane = tid & 63, lr = lane & 15, g = lane >> 4;
    const int wr = wave >> 1, wc = wave & 1;
    const int row0 = blockIdx.y * 128, col0 = blockIdx.x * 128;

    // staging: wave w stages tile w; lane covers (row chunk*16 + (lane>>2),
    // dest granule lane&3); source granule = dest ^ ((row>>1)&3) = (lane&3)^((lane>>3)&3)
    const int drow = lane >> 2;
    const int sgr  = ((lane & 3) ^ ((lane >> 3) & 3)) * 8;   // ushort offset
    const unsigned short* tsrc =
        (wave == 0) ? Xh  + (size_t)(row0 + drow) * 1024 + sgr :
        (wave == 1) ? Xm  + (size_t)(row0 + drow) * 1024 + sgr :
        (wave == 2) ? WTh + (size_t)(col0 + drow) * 1024 + sgr :
                      WTm + (size_t)(col0 + drow) * 1024 + sgr;

    #define STAGE(buf, t)                                                        \
        _Pragma("unroll")                                                        \
        for (int c = 0; c < 8; ++c)                                              \
            async_copy16(tsrc + (size_t)(c * 16) * 1024 + (t) * 32,              \
                         &LDS[buf][wave][c * 16 * 32]);

    f32x4 acc[4][4] = {};

    // read granule (swizzled): row = *+lr -> key = (lr>>1)&3
    const int rgr = (g ^ ((lr >> 1) & 3)) * 8;

    STAGE(0, 0);
    __syncthreads();   // vmcnt(0) drain: tile 0 in LDS

    for (int t = 0; t < 32; ++t) {
        const int cur = t & 1;
        if (t < 31) { STAGE(cur ^ 1, t + 1); }   // prefetch flies under compute

        bf16x8 axh[4], axm[4], bwh[4], bwm[4];
        #pragma unroll
        for (int mf = 0; mf < 4; ++mf) {
            axh[mf] = *(const bf16x8*)&LDS[cur][0][(wr * 64 + mf * 16 + lr) * 32 + rgr];
            axm[mf] = *(const bf16x8*)&LDS[cur][1][(wr * 64 + mf * 16 + lr) * 32 + rgr];
        }
        #pragma unroll
        for (int nf = 0; nf < 4; ++nf) {
            bwh[nf] = *(const bf16x8*)&LDS[cur][2][(wc * 64 + nf * 16 + lr) * 32 + rgr];
            bwm[nf] = *(const bf16x8*)&LDS[cur][3][(wc * 64 + nf * 16 + lr) * 32 + rgr];
        }
        #pragma unroll
        for (int nf = 0; nf < 4; ++nf) {
            #pragma unroll
            for (int mf = 0; mf < 4; ++mf)
                acc[mf][nf] = __builtin_amdgcn_mfma_f32_16x16x32_bf16(
                    axh[mf], bwh[nf], acc[mf][nf], 0, 0, 0);
            #pragma unroll
            for (int mf = 0; mf < 4; ++mf)
                acc[mf][nf] = __builtin_amdgcn_mfma_f32_16x16x32_bf16(
                    axh[mf], bwm[nf], acc[mf][nf], 0, 0, 0);
            #pragma unroll
            for (int mf = 0; mf < 4; ++mf)
                acc[mf][nf] = __builtin_amdgcn_mfma_f32_16x16x32_bf16(
                    axm[mf], bwh[nf], acc[mf][nf], 0, 0, 0);
        }
        __syncthreads();   // drains vmcnt(0): tile t+1 ready; buf[cur] reusable
    }
    #undef STAGE

    // ================= epilogue =================
    // C frag: row = wr*64+m*16+g*4+r, col = wc*64+n*16+lr
    const int which = col0 >> 10;
    const int hcol  = ((col0 + wc * 64) & 1023) >> 6;
    const int b     = row0 >> 11;
    const int s_base = (row0 & 2047) + wr * 64;

    float bo[4];
    #pragma unroll
    for (int n = 0; n < 4; ++n) bo[n] = bias[col0 + wc * 64 + n * 16 + lr];
    #pragma unroll
    for (int m = 0; m < 4; ++m)
        #pragma unroll
        for (int n = 0; n < 4; ++n)
            #pragma unroll
            for (int r = 0; r < 4; ++r)
                acc[m][n][r] += bo[n];

    if (which == 0) {
        unsigned short* qdst = Qb + (((size_t)b * NHEAD + hcol) * SEQ) * 64;
        #pragma unroll
        for (int m = 0; m < 4; ++m)
            #pragma unroll
            for (int r = 0; r < 4; ++r) {
                int s = s_base + m * 16 + g * 4 + r;
                #pragma unroll
                for (int n = 0; n < 4; ++n)
                    qdst[(size_t)s * 64 + n * 16 + lr] = f2bf(acc[m][n][r]);
            }
    } else if (which == 1) {
        // key quant: per-channel min/max over this wave's 64 tokens
        #pragma unroll
        for (int n = 0; n < 4; ++n) {
            float cmn = INFINITY, cmx = -INFINITY;
            #pragma unroll
            for (int m = 0; m < 4; ++m)
                #pragma unroll
                for (int r = 0; r < 4; ++r) {
                    float v = clipf(acc[m][n][r]);
                    acc[m][n][r] = v;
                    cmn = fminf(cmn, v); cmx = fmaxf(cmx, v);
                }
            cmn = fminf(cmn, __shfl_xor(cmn, 16)); cmx = fmaxf(cmx, __shfl_xor(cmx, 16));
            cmn = fminf(cmn, __shfl_xor(cmn, 32)); cmx = fmaxf(cmx, __shfl_xor(cmx, 32));
            float scale = fmaxf((cmx - cmn) / 3.0f, 1e-8f);
            float tol = 0.5f - 1e-3f / scale;
            #pragma unroll
            for (int m = 0; m < 4; ++m)
                #pragma unroll
                for (int r = 0; r < 4; ++r) {
                    float f = (acc[m][n][r] - cmn) / scale;
                    float qv = rintf(f);
                    if (fabsf(f - qv) > tol) {
                        int s  = s_base + m * 16 + g * 4 + r;
                        int mg = row0 + wr * 64 + m * 16 + g * 4 + r;
                        int ng = col0 + wc * 64 + n * 16 + lr;
                        unsigned dst = 4194304u +
                            (unsigned)(((b * NHEAD + hcol) * SEQ + s) * 64 + n * 16 + lr);
                        push_flag(cnt, recs, dst, mg, ng, cmn, scale);
                    }
                    acc[m][n][r] = qv * scale + cmn;
                }
        }
        unsigned short* kdst = Kb + (((size_t)b * NHEAD + hcol) * SEQ) * 64;
        #pragma unroll
        for (int m = 0; m < 4; ++m)
            #pragma unroll
            for (int r = 0; r < 4; ++r) {
                int s = s_base + m * 16 + g * 4 + r;
                #pragma unroll
                for (int n = 0; n < 4; ++n)
                    kdst[(size_t)s * 64 + n * 16 + lr] = f2bf(acc[m][n][r]);
            }
    } else {
        // value quant: per-token min/max over 64 channels; s < VQL only
        #pragma unroll
        for (int m = 0; m < 4; ++m)
            #pragma unroll
            for (int r = 0; r < 4; ++r) {
                float c[4];
                #pragma unroll
                for (int n = 0; n < 4; ++n) c[n] = clipf(acc[m][n][r]);
                float mn = fminf(fminf(c[0], c[1]), fminf(c[2], c[3]));
                float mx = fmaxf(fmaxf(c[0], c[1]), fmaxf(c[2], c[3]));
                #pragma unroll
                for (int msk = 1; msk < 16; msk <<= 1) {
                    mn = fminf(mn, __shfl_xor(mn, msk));
                    mx = fmaxf(mx, __shfl_xor(mx, msk));
                }
                int s = s_base + m * 16 + g * 4 + r;
                if (s < VQL) {
                    float scale = fmaxf((mx - mn) / 3.0f, 1e-8f);
                    float tol = 0.5f - 1e-3f / scale;
                    #pragma unroll
                    for (int n = 0; n < 4; ++n) {
                        float f = (c[n] - mn) / scale;
                        float qv = rintf(f);
                        if (fabsf(f - qv) > tol) {
                            int mg = row0 + wr * 64 + m * 16 + g * 4 + r;
                            int ng = col0 + wc * 64 + n * 16 + lr;
                            unsigned dst = 8388608u +
                                (unsigned)((((b * NHEAD + hcol) * 64) + n * 16 + lr) * SEQ + s);
                            push_flag(cnt, recs, dst, mg, ng, mn, scale);
                        }
                        acc[m][n][r] = qv * scale + mn;
                    }
                }
                // else raw unclipped tail (acc keeps bias-added value)
            }
        #pragma unroll
        for (int m = 0; m < 4; ++m)
            #pragma unroll
            for (int n = 0; n < 4; ++n) {
                ushort4_t o;
                #pragma unroll
                for (int r = 0; r < 4; ++r) o[r] = f2bf(acc[m][n][r]);
                *(ushort4_t*)(Vt + ((((size_t)b * NHEAD + hcol) * 64) + n * 16 + lr) * SEQ
                                 + s_base + m * 16 + g * 4) = o;
            }
    }
}

// ---------------------------------------------------------------------------
// Boundary repair: one wave per record; exact fp32 dot, requantize with the
// SAME group's mn/scale, rewrite the single bf16 element. Order-independent.
// ---------------------------------------------------------------------------
__global__ __launch_bounds__(256) void repair_kernel(
    const float* __restrict__ X,
    const unsigned short* __restrict__ WTh, const unsigned short* __restrict__ WTm,
    const unsigned short* __restrict__ WTl,
    const float* __restrict__ bias, unsigned short* __restrict__ wsu,
    const unsigned* __restrict__ cnt, const Rec* __restrict__ recs)
{
    const int lane = threadIdx.x & 63;
    const int wid  = blockIdx.x * 4 + (threadIdx.x >> 6);
    unsigned nrec = *cnt; if (nrec > REC_CAP) nrec = REC_CAP;
    for (unsigned i = wid; i < nrec; i += gridDim.x * 4) {
        Rec rc = recs[i];
        int mg = rc.mn_pack & 4095;
        int ng = (rc.mn_pack >> 12) & 4095;
        const float* xr          = X   + (size_t)mg * 1024 + lane * 16;
        const unsigned short* wh = WTh + (size_t)ng * 1024 + lane * 16;
        const unsigned short* wm = WTm + (size_t)ng * 1024 + lane * 16;
        const unsigned short* wl = WTl + (size_t)ng * 1024 + lane * 16;
        float s = 0.f;
        #pragma unroll
        for (int j4 = 0; j4 < 4; ++j4) {
            float4 xv = *(const float4*)(xr + j4 * 4);
            float xs[4] = {xv.x, xv.y, xv.z, xv.w};
            #pragma unroll
            for (int e = 0; e < 4; ++e) {
                int j = j4 * 4 + e;
                s += xs[e] * (bf2f(wh[j]) + bf2f(wm[j]) + bf2f(wl[j]));
            }
        }
        #pragma unroll
        for (int msk = 1; msk < 64; msk <<= 1) s += __shfl_xor(s, msk);
        if (lane == 0) {
            float v = clipf(s + bias[ng]);
            float val = rintf((v - rc.mn) / rc.scale) * rc.scale + rc.mn;
            wsu[rc.dst] = f2bf(val);
        }
    }
}

// ---------------------------------------------------------------------------
// MFMA flash attention (bf16, fp32 accum), causal, scale 1/8. (unchanged)
// ---------------------------------------------------------------------------
__global__ __launch_bounds__(256) void attn_mfma(
    unsigned short* __restrict__ QY,
    const unsigned short* __restrict__ K,
    const unsigned short* __restrict__ Vt)
{
    __shared__ unsigned short Ks [64][72];
    __shared__ unsigned short VsT[64][72];
    __shared__ unsigned short Ps [4][16][72];

    const int tid  = threadIdx.x;
    const int wave = tid >> 6;
    const int lane = tid & 63;
    const int lr   = lane & 15;
    const int g    = lane >> 4;

    const int bid = blockIdx.x;
    const int qt  = 31 - (bid >> 5);
    const int bh  = bid & 31;
    const size_t base = (size_t)bh * (SEQ * 64);

    const int qrow = qt * 64 + wave * 16 + lr;
    const unsigned short* qp = QY + base + (size_t)qrow * 64;
    bf16x8 aq[2];
    #pragma unroll
    for (int ka = 0; ka < 2; ++ka)
        aq[ka] = *(const bf16x8*)(qp + ka * 32 + g * 8);

    f32x4 o[4] = {};
    float m[4]    = {-1e30f, -1e30f, -1e30f, -1e30f};
    float lsum[4] = {};
    const float sc = 0.125f;

    const int str = tid >> 2;
    const int stc = (tid & 3) << 4;

    for (int jt = 0; jt <= qt; ++jt) {
        __syncthreads();
        {
            const unsigned short* kg = K + base + ((size_t)(jt * 64 + str) << 6) + stc;
            *(ushort8_t*)&Ks[str][stc]     = *(const ushort8_t*)kg;
            *(ushort8_t*)&Ks[str][stc + 8] = *(const ushort8_t*)(kg + 8);
            const unsigned short* vg = Vt + base + ((size_t)str << 11) + jt * 64 + stc;
            *(ushort8_t*)&VsT[str][stc]     = *(const ushort8_t*)vg;
            *(ushort8_t*)&VsT[str][stc + 8] = *(const ushort8_t*)(vg + 8);
        }
        __syncthreads();

        f32x4 s[4] = {};
        #pragma unroll
        for (int f = 0; f < 4; ++f) {
            #pragma unroll
            for (int ka = 0; ka < 2; ++ka) {
                bf16x8 bk = *(const bf16x8*)&Ks[f * 16 + lr][ka * 32 + g * 8];
                s[f] = __builtin_amdgcn_mfma_f32_16x16x32_bf16(aq[ka], bk, s[f], 0, 0, 0);
            }
        }

        const bool diag = (jt == qt);
        float mx[4];
        #pragma unroll
        for (int r = 0; r < 4; ++r) {
            const int ql = wave * 16 + g * 4 + r;
            float vmax = -1e30f;
            #pragma unroll
            for (int f = 0; f < 4; ++f) {
                float v = s[f][r] * sc;
                if (diag && (f * 16 + lr) > ql) v = -1e30f;
                s[f][r] = v;
                vmax = fmaxf(vmax, v);
            }
            mx[r] = vmax;
        }
        #pragma unroll
        for (int msk = 1; msk < 16; msk <<= 1)
            #pragma unroll
            for (int r = 0; r < 4; ++r)
                mx[r] = fmaxf(mx[r], __shfl_xor(mx[r], msk));

        float alpha[4], tsum[4];
        #pragma unroll
        for (int r = 0; r < 4; ++r) {
            float mn = fmaxf(m[r], mx[r]);
            alpha[r] = __expf(m[r] - mn);
            m[r] = mn;
            float ts = 0.0f;
            #pragma unroll
            for (int f = 0; f < 4; ++f) {
                float p = __expf(s[f][r] - mn);
                unsigned short ub = f2bf(p);
                Ps[wave][g * 4 + r][f * 16 + lr] = ub;
                ts += bf2f(ub);
            }
            tsum[r] = ts;
        }
        #pragma unroll
        for (int msk = 1; msk < 16; msk <<= 1)
            #pragma unroll
            for (int r = 0; r < 4; ++r)
                tsum[r] += __shfl_xor(tsum[r], msk);
        #pragma unroll
        for (int r = 0; r < 4; ++r) {
            lsum[r] = lsum[r] * alpha[r] + tsum[r];
            #pragma unroll
            for (int df = 0; df < 4; ++df) o[df][r] *= alpha[r];
        }

        asm volatile("s_waitcnt lgkmcnt(0)" ::: "memory");
        __builtin_amdgcn_sched_barrier(0);

        bf16x8 pa[2];
        #pragma unroll
        for (int kb = 0; kb < 2; ++kb)
            pa[kb] = *(const bf16x8*)&Ps[wave][lr][kb * 32 + g * 8];
        #pragma unroll
        for (int df = 0; df < 4; ++df) {
            #pragma unroll
            for (int kb = 0; kb < 2; ++kb) {
                bf16x8 vb = *(const bf16x8*)&VsT[df * 16 + lr][kb * 32 + g * 8];
                o[df] = __builtin_amdgcn_mfma_f32_16x16x32_bf16(pa[kb], vb, o[df], 0, 0, 0);
            }
        }
    }

    float invl[4];
    #pragma unroll
    for (int r = 0; r < 4; ++r) invl[r] = 1.0f / lsum[r];
    #pragma unroll
    for (int df = 0; df < 4; ++df)
        #pragma unroll
        for (int r = 0; r < 4; ++r) {
            int q = qt * 64 + wave * 16 + g * 4 + r;
            QY[base + (size_t)q * 64 + df * 16 + lr] = f2bf(o[df][r] * invl[r]);
        }
}

// ---------------------------------------------------------------------------
// Proj GEMM via bf16 MFMA (unchanged).
// ---------------------------------------------------------------------------
#define PJ_PAD 72
__global__ __launch_bounds__(256, 2) void gemm_proj_mfma(
    const unsigned short* __restrict__ Y, const float* __restrict__ W,
    const float* __restrict__ bias, float* __restrict__ C)
{
    __shared__ unsigned short A2[2][128][PJ_PAD];
    __shared__ unsigned short B2[2][128][PJ_PAD];

    const int tid  = threadIdx.x;
    const int wave = tid >> 6, lane = tid & 63, lr = lane & 15, g = lane >> 4;
    const int wr = wave >> 1, wc = wave & 1;
    const int row0 = blockIdx.y * 128, col0 = blockIdx.x * 128;
    const int b = row0 >> 11, s0 = row0 & 2047;

    const int ra  = tid >> 1,       ca  = (tid & 1) * 32;
    const int cb4 = (tid & 31) * 4, kb4 = (tid >> 5) * 4;

    ushort8_t a_reg[4];
    float bw[2][4][4];

    {
        const unsigned short* gy = Y + ((((size_t)b * NHEAD + 0) * SEQ + s0 + ra) << 6) + ca;
        #pragma unroll
        for (int i = 0; i < 4; ++i) a_reg[i] = *(const ushort8_t*)(gy + i * 8);
        const float* gw = W + (size_t)kb4 * EMB + col0 + cb4;
        #pragma unroll
        for (int half = 0; half < 2; ++half)
            #pragma unroll
            for (int i = 0; i < 4; ++i)
                *(float4*)bw[half][i] = *(const float4*)(gw + (size_t)(half * 32 + i) * EMB);
        #pragma unroll
        for (int i = 0; i < 4; ++i) *(ushort8_t*)&A2[0][ra][ca + i * 8] = a_reg[i];
        #pragma unroll
        for (int half = 0; half < 2; ++half)
            #pragma unroll
            for (int j = 0; j < 4; ++j) {
                unsigned w2[2];
                w2[0] = cvtpk(bw[half][0][j], bw[half][1][j]);
                w2[1] = cvtpk(bw[half][2][j], bw[half][3][j]);
                *(uint2_t*)&B2[0][cb4 + j][half * 32 + kb4] = *(uint2_t*)w2;
            }
    }
    __syncthreads();

    f32x4 acc[4][4] = {};

    for (int t = 0; t < 16; ++t) {
        const int cur = t & 1;
        if (t < 15) {
            const unsigned short* gy =
                Y + ((((size_t)b * NHEAD + (t + 1)) * SEQ + s0 + ra) << 6) + ca;
            #pragma unroll
            for (int i = 0; i < 4; ++i) a_reg[i] = *(const ushort8_t*)(gy + i * 8);
            const float* gw = W + (size_t)((t + 1) * 64 + kb4) * EMB + col0 + cb4;
            #pragma unroll
            for (int half = 0; half < 2; ++half)
                #pragma unroll
                for (int i = 0; i < 4; ++i)
                    *(float4*)bw[half][i] = *(const float4*)(gw + (size_t)(half * 32 + i) * EMB);
        }
        #pragma unroll
        for (int kk = 0; kk < 2; ++kk) {
            bf16x8 af[4];
            #pragma unroll
            for (int m = 0; m < 4; ++m)
                af[m] = *(const bf16x8*)&A2[cur][wr * 64 + m * 16 + lr][kk * 32 + g * 8];
            #pragma unroll
            for (int n = 0; n < 4; ++n) {
                bf16x8 bf = *(const bf16x8*)&B2[cur][wc * 64 + n * 16 + lr][kk * 32 + g * 8];
                #pragma unroll
                for (int m = 0; m < 4; ++m)
                    acc[m][n] = __builtin_amdgcn_mfma_f32_16x16x32_bf16(af[m], bf, acc[m][n], 0, 0, 0);
            }
        }
        if (t < 15) {
            const int nxt = cur ^ 1;
            #pragma unroll
            for (int i = 0; i < 4; ++i) *(ushort8_t*)&A2[nxt][ra][ca + i * 8] = a_reg[i];
            #pragma unroll
            for (int half = 0; half < 2; ++half)
                #pragma unroll
                for (int j = 0; j < 4; ++j) {
                    unsigned w2[2];
                    w2[0] = cvtpk(bw[half][0][j], bw[half][1][j]);
                    w2[1] = cvtpk(bw[half][2][j], bw[half][3][j]);
                    *(uint2_t*)&B2[nxt][cb4 + j][half * 32 + kb4] = *(uint2_t*)w2;
                }
        }
        __syncthreads();
    }

    float bo[4];
    #pragma unroll
    for (int n = 0; n < 4; ++n) bo[n] = bias[col0 + wc * 64 + n * 16 + lr];
    #pragma unroll
    for (int m = 0; m < 4; ++m)
        #pragma unroll
        for (int r = 0; r < 4; ++r) {
            int mrow = row0 + wr * 64 + m * 16 + g * 4 + r;
            #pragma unroll
            for (int n = 0; n < 4; ++n)
                C[(size_t)mrow * EMB + col0 + wc * 64 + n * 16 + lr] = acc[m][n][r] + bo[n];
        }
}

// ---------------------------------------------------------------------------
extern "C" void kernel_launch(void* const* d_in, const int* in_sizes, int n_in,
                              void* d_out, int out_size, void* d_ws, size_t ws_size,
                              hipStream_t stream)
{
    const float* x     = (const float*)d_in[0];
    const float* Wqkv  = (const float*)d_in[1];
    const float* bqkv  = (const float*)d_in[2];
    const float* Wproj = (const float*)d_in[3];
    const float* bproj = (const float*)d_in[4];
    float* out = (float*)d_out;

    // Workspace layout (~59.2 MiB total):
    //  [0,8)    MiB q bf16 [B,H,S,D] (y overwrites)
    //  [8,16)   MiB k bf16 [B,H,S,D]
    //  [16,24)  MiB v bf16 [B,H,D,S]
    //  [24,32)  MiB Xh   [32,40) Xm        bf16 [4096][1024]
    //  [40,46)  MiB WTh  [46,52) WTm  [52,58) WTl  bf16 [3072][1024]
    //  [58 MiB) counter + records
    char* ws = (char*)d_ws;
    unsigned short* q   = (unsigned short*)ws;
    unsigned short* kb  = (unsigned short*)(ws + (8u  << 20));
    unsigned short* vt  = (unsigned short*)(ws + (16u << 20));
    unsigned short* Xh  = (unsigned short*)(ws + (24u << 20));
    unsigned short* Xm  = (unsigned short*)(ws + (32u << 20));
    unsigned short* WTh = (unsigned short*)(ws + (40u << 20));
    unsigned short* WTm = (unsigned short*)(ws + (46u << 20));
    unsigned short* WTl = (unsigned short*)(ws + (52u << 20));
    unsigned*       cnt = (unsigned*)(ws + (58u << 20));
    Rec*           recs = (Rec*)(ws + (58u << 20) + 256);

    zero_cnt_kernel<<<1, 64, 0, stream>>>(cnt);
    split_x_kernel<<<2048, 256, 0, stream>>>(x, Xh, Xm);
    split_wt_kernel<<<dim3(48, 16), 256, 0, stream>>>(Wqkv, WTh, WTm, WTl);
    gemm_qkv3<<<dim3(N3E / 128, 4096 / 128), 256, 0, stream>>>(
        Xh, Xm, WTh, WTm, bqkv, q, kb, vt, cnt, recs);
    repair_kernel<<<128, 256, 0, stream>>>(x, WTh, WTm, WTl, bqkv,
                                           (unsigned short*)d_ws, cnt, recs);
    attn_mfma<<<dim3(32 * 32), 256, 0, stream>>>(q, kb, vt);
    gemm_proj_mfma<<<dim3(EMB / 128, 4096 / 128), 256, 0, stream>>>(q, Wproj, bproj, out);
}

// Round 8
// 321.857 us; speedup vs baseline: 1.1210x; 1.0650x over previous
//
#include <hip/hip_runtime.h>
#include <math.h>

// Problem constants
#define BATCH 2
#define SEQ   2048
#define NHEAD 16
#define EMB   1024
#define N3E   3072
#define VQL   2016   // SEQ - RESIDUAL_LEN
#define REC_CAP 65536

typedef unsigned short ushort8_t __attribute__((ext_vector_type(8)));
typedef unsigned short ushort4_t __attribute__((ext_vector_type(4)));
typedef short bf16x8 __attribute__((ext_vector_type(8)));
typedef float f32x4 __attribute__((ext_vector_type(4)));
typedef unsigned int uint2_t __attribute__((ext_vector_type(2)));

struct __align__(16) Rec { unsigned dst; unsigned mn_pack; float mn; float scale; };

__device__ __forceinline__ float clipf(float x) {
    return fminf(fmaxf(x, -10000.0f), 10000.0f);
}
__device__ __forceinline__ float bf2f(unsigned short u) {
    return __uint_as_float(((unsigned)u) << 16);
}
__device__ __forceinline__ unsigned short f2bf(float f) {  // round-to-nearest-even
    unsigned u = __float_as_uint(f);
    unsigned r = 0x7FFFu + ((u >> 16) & 1u);
    return (unsigned short)((u + r) >> 16);
}
__device__ __forceinline__ unsigned cvtpk(float lo, float hi) {
    unsigned r;
    asm("v_cvt_pk_bf16_f32 %0, %1, %2" : "=v"(r) : "v"(lo), "v"(hi));
    return r;
}
// async global->LDS, 16B per lane; LDS dest must be wave-uniform base
__device__ __forceinline__ void async_copy16(const unsigned short* g, unsigned short* lds) {
    __builtin_amdgcn_global_load_lds(
        (const __attribute__((address_space(1))) unsigned int*)g,
        (__attribute__((address_space(3))) unsigned int*)lds, 16, 0, 0);
}

// ---------------------------------------------------------------------------
// Pre-split X: fp32 [4096][1024] -> Xh, Xm bf16 (x = hi + mid + eps, eps~2^-18)
// Also zeroes the repair-record counter (block 0), replacing zero_cnt_kernel.
// ---------------------------------------------------------------------------
__global__ __launch_bounds__(256) void split_x_kernel(
    const float* __restrict__ X,
    unsigned short* __restrict__ Xh, unsigned short* __restrict__ Xm,
    unsigned* __restrict__ cnt)
{
    if (blockIdx.x == 0 && threadIdx.x == 0) *cnt = 0;
    const size_t i8 = ((size_t)blockIdx.x * 256 + threadIdx.x) * 8;
    float4 a = *(const float4*)(X + i8);
    float4 b = *(const float4*)(X + i8 + 4);
    float xs[8] = {a.x, a.y, a.z, a.w, b.x, b.y, b.z, b.w};
    ushort8_t h8, m8;
    #pragma unroll
    for (int j = 0; j < 8; ++j) {
        unsigned short h = f2bf(xs[j]);
        h8[j] = h;
        m8[j] = f2bf(xs[j] - bf2f(h));
    }
    *(ushort8_t*)(Xh + i8) = h8;
    *(ushort8_t*)(Xm + i8) = m8;
}

// ---------------------------------------------------------------------------
// Pre-split + transpose W_qkv: fp32 [1024][3072] -> WTh/WTm/WTl bf16 [3072][1024]
// ---------------------------------------------------------------------------
__global__ __launch_bounds__(256) void split_wt_kernel(
    const float* __restrict__ W,
    unsigned short* __restrict__ WTh, unsigned short* __restrict__ WTm,
    unsigned short* __restrict__ WTl)
{
    __shared__ float t[64][65];
    const int tid = threadIdx.x;
    const int nt = blockIdx.x * 64, kt = blockIdx.y * 64;
    const int r = tid >> 2, cg = (tid & 3) * 16;
    #pragma unroll
    for (int j = 0; j < 4; ++j) {
        float4 v = *(const float4*)(W + (size_t)(kt + r) * N3E + nt + cg + j * 4);
        t[r][cg + j * 4 + 0] = v.x; t[r][cg + j * 4 + 1] = v.y;
        t[r][cg + j * 4 + 2] = v.z; t[r][cg + j * 4 + 3] = v.w;
    }
    __syncthreads();
    ushort8_t h8[2], m8[2], l8[2];
    #pragma unroll
    for (int j = 0; j < 16; ++j) {
        float v = t[cg + j][r];
        unsigned short h = f2bf(v);
        float r1 = v - bf2f(h);
        unsigned short mm = f2bf(r1);
        float r2 = r1 - bf2f(mm);
        h8[j >> 3][j & 7] = h; m8[j >> 3][j & 7] = mm; l8[j >> 3][j & 7] = f2bf(r2);
    }
    size_t off = (size_t)(nt + r) * 1024 + kt + cg;
    *(ushort8_t*)(WTh + off) = h8[0]; *(ushort8_t*)(WTh + off + 8) = h8[1];
    *(ushort8_t*)(WTm + off) = m8[0]; *(ushort8_t*)(WTm + off + 8) = m8[1];
    *(ushort8_t*)(WTl + off) = l8[0]; *(ushort8_t*)(WTl + off + 8) = l8[1];
}

__device__ __forceinline__ void push_flag(unsigned* cnt, Rec* recs, unsigned dst,
                                          int mg, int ng, float mn, float scale) {
    unsigned idx = atomicAdd(cnt, 1u);
    if (idx < REC_CAP) {
        Rec r; r.dst = dst; r.mn_pack = (unsigned)mg | ((unsigned)ng << 12);
        r.mn = mn; r.scale = scale;
        recs[idx] = r;
    }
}

// ---------------------------------------------------------------------------
// QKV GEMM, fused 3-product split (XhWh + XhWm + XmWh, err ~2^-18), KIVI quant
// epilogue with boundary flagging. 128x128 tile, BK=32, 4 waves (2x2 of 64x64).
// T3+T4 pipeline: depth-2 prefetch, COUNTED vmcnt (never 0 in steady state),
// raw s_barrier (no vmcnt(0) drain). Per iter:
//   vmcnt(8) -> barrier -> ds_read frags -> lgkmcnt(0)+sched_barrier ->
//   barrier -> STAGE(t+2) into freed buffer -> 48 MFMA.
// LDS tile row = 32 ushorts (64B) = 4 granules of 16B; granule XOR key
// (row>>1)&3 applied on the global SOURCE and on ds_read (0 conflicts, R7).
// ---------------------------------------------------------------------------
__global__ __launch_bounds__(256, 2) void gemm_qkv3(
    const unsigned short* __restrict__ Xh, const unsigned short* __restrict__ Xm,
    const unsigned short* __restrict__ WTh, const unsigned short* __restrict__ WTm,
    const float* __restrict__ bias,
    unsigned short* __restrict__ Qb, unsigned short* __restrict__ Kb,
    unsigned short* __restrict__ Vt,
    unsigned* __restrict__ cnt, Rec* __restrict__ recs)
{
    // [buf][tile: 0=XhA 1=XmA 2=WhB 3=WmB][128 rows * 32 cols]
    __shared__ __align__(16) unsigned short LDS[2][4][128 * 32];

    const int tid  = threadIdx.x;
    const int wave = tid >> 6, lane = tid & 63, lr = lane & 15, g = lane >> 4;
    const int wr = wave >> 1, wc = wave & 1;
    const int row0 = blockIdx.y * 128, col0 = blockIdx.x * 128;

    // staging: wave w stages tile w; lane covers (rows chunk*16+(lane>>2),
    // dest granule lane&3); source granule = dest ^ ((row>>1)&3)
    const int drow = lane >> 2;
    const int sgr  = ((lane & 3) ^ ((lane >> 3) & 3)) * 8;   // ushort offset
    const unsigned short* tsrc =
        (wave == 0) ? Xh  + (size_t)(row0 + drow) * 1024 + sgr :
        (wave == 1) ? Xm  + (size_t)(row0 + drow) * 1024 + sgr :
        (wave == 2) ? WTh + (size_t)(col0 + drow) * 1024 + sgr :
                      WTm + (size_t)(col0 + drow) * 1024 + sgr;

    #define STAGE(buf, t)                                                        \
        _Pragma("unroll")                                                        \
        for (int c = 0; c < 8; ++c)                                              \
            async_copy16(tsrc + (size_t)(c * 16) * 1024 + (t) * 32,              \
                         &LDS[buf][wave][c * 16 * 32]);

    f32x4 acc[4][4] = {};

    // read granule (swizzled): frag row = 16*a + lr -> key = (lr>>1)&3
    const int rgr = (g ^ ((lr >> 1) & 3)) * 8;

    STAGE(0, 0);            // 8 loads in flight
    STAGE(1, 1);            // 16 in flight

    for (int t = 0; t < 32; ++t) {
        const int cur = t & 1;
        if (t < 31) {
            asm volatile("s_waitcnt vmcnt(8)" ::: "memory");   // tile t done; t+1 in flight
        } else {
            asm volatile("s_waitcnt vmcnt(0)" ::: "memory");   // final tile
        }
        __builtin_amdgcn_s_barrier();   // all waves' tile-t loads visible

        bf16x8 axh[4], axm[4], bwh[4], bwm[4];
        #pragma unroll
        for (int mf = 0; mf < 4; ++mf) {
            axh[mf] = *(const bf16x8*)&LDS[cur][0][(wr * 64 + mf * 16 + lr) * 32 + rgr];
            axm[mf] = *(const bf16x8*)&LDS[cur][1][(wr * 64 + mf * 16 + lr) * 32 + rgr];
        }
        #pragma unroll
        for (int nf = 0; nf < 4; ++nf) {
            bwh[nf] = *(const bf16x8*)&LDS[cur][2][(wc * 64 + nf * 16 + lr) * 32 + rgr];
            bwm[nf] = *(const bf16x8*)&LDS[cur][3][(wc * 64 + nf * 16 + lr) * 32 + rgr];
        }
        asm volatile("s_waitcnt lgkmcnt(0)" ::: "memory");     // frags in regs
        __builtin_amdgcn_sched_barrier(0);                     // rule 18
        __builtin_amdgcn_s_barrier();   // all waves done reading buf[cur]

        if (t < 30) { STAGE(cur, t + 2); }   // refill freed buffer; back to 16 in flight

        #pragma unroll
        for (int nf = 0; nf < 4; ++nf) {
            #pragma unroll
            for (int mf = 0; mf < 4; ++mf)
                acc[mf][nf] = __builtin_amdgcn_mfma_f32_16x16x32_bf16(
                    axh[mf], bwh[nf], acc[mf][nf], 0, 0, 0);
            #pragma unroll
            for (int mf = 0; mf < 4; ++mf)
                acc[mf][nf] = __builtin_amdgcn_mfma_f32_16x16x32_bf16(
                    axh[mf], bwm[nf], acc[mf][nf], 0, 0, 0);
            #pragma unroll
            for (int mf = 0; mf < 4; ++mf)
                acc[mf][nf] = __builtin_amdgcn_mfma_f32_16x16x32_bf16(
                    axm[mf], bwh[nf], acc[mf][nf], 0, 0, 0);
        }
    }
    #undef STAGE

    // ================= epilogue =================
    // C frag: row = wr*64+m*16+g*4+r, col = wc*64+n*16+lr
    const int which = col0 >> 10;
    const int hcol  = ((col0 + wc * 64) & 1023) >> 6;
    const int b     = row0 >> 11;
    const int s_base = (row0 & 2047) + wr * 64;

    float bo[4];
    #pragma unroll
    for (int n = 0; n < 4; ++n) bo[n] = bias[col0 + wc * 64 + n * 16 + lr];
    #pragma unroll
    for (int m = 0; m < 4; ++m)
        #pragma unroll
        for (int n = 0; n < 4; ++n)
            #pragma unroll
            for (int r = 0; r < 4; ++r)
                acc[m][n][r] += bo[n];

    if (which == 0) {
        unsigned short* qdst = Qb + (((size_t)b * NHEAD + hcol) * SEQ) * 64;
        #pragma unroll
        for (int m = 0; m < 4; ++m)
            #pragma unroll
            for (int r = 0; r < 4; ++r) {
                int s = s_base + m * 16 + g * 4 + r;
                #pragma unroll
                for (int n = 0; n < 4; ++n)
                    qdst[(size_t)s * 64 + n * 16 + lr] = f2bf(acc[m][n][r]);
            }
    } else if (which == 1) {
        // key quant: per-channel min/max over this wave's 64 tokens
        #pragma unroll
        for (int n = 0; n < 4; ++n) {
            float cmn = INFINITY, cmx = -INFINITY;
            #pragma unroll
            for (int m = 0; m < 4; ++m)
                #pragma unroll
                for (int r = 0; r < 4; ++r) {
                    float v = clipf(acc[m][n][r]);
                    acc[m][n][r] = v;
                    cmn = fminf(cmn, v); cmx = fmaxf(cmx, v);
                }
            cmn = fminf(cmn, __shfl_xor(cmn, 16)); cmx = fmaxf(cmx, __shfl_xor(cmx, 16));
            cmn = fminf(cmn, __shfl_xor(cmn, 32)); cmx = fmaxf(cmx, __shfl_xor(cmx, 32));
            float scale = fmaxf((cmx - cmn) / 3.0f, 1e-8f);
            float tol = 0.5f - 1e-3f / scale;
            #pragma unroll
            for (int m = 0; m < 4; ++m)
                #pragma unroll
                for (int r = 0; r < 4; ++r) {
                    float f = (acc[m][n][r] - cmn) / scale;
                    float qv = rintf(f);
                    if (fabsf(f - qv) > tol) {
                        int s  = s_base + m * 16 + g * 4 + r;
                        int mg = row0 + wr * 64 + m * 16 + g * 4 + r;
                        int ng = col0 + wc * 64 + n * 16 + lr;
                        unsigned dst = 4194304u +
                            (unsigned)(((b * NHEAD + hcol) * SEQ + s) * 64 + n * 16 + lr);
                        push_flag(cnt, recs, dst, mg, ng, cmn, scale);
                    }
                    acc[m][n][r] = qv * scale + cmn;
                }
        }
        unsigned short* kdst = Kb + (((size_t)b * NHEAD + hcol) * SEQ) * 64;
        #pragma unroll
        for (int m = 0; m < 4; ++m)
            #pragma unroll
            for (int r = 0; r < 4; ++r) {
                int s = s_base + m * 16 + g * 4 + r;
                #pragma unroll
                for (int n = 0; n < 4; ++n)
                    kdst[(size_t)s * 64 + n * 16 + lr] = f2bf(acc[m][n][r]);
            }
    } else {
        // value quant: per-token min/max over 64 channels; s < VQL only
        #pragma unroll
        for (int m = 0; m < 4; ++m)
            #pragma unroll
            for (int r = 0; r < 4; ++r) {
                float c[4];
                #pragma unroll
                for (int n = 0; n < 4; ++n) c[n] = clipf(acc[m][n][r]);
                float mn = fminf(fminf(c[0], c[1]), fminf(c[2], c[3]));
                float mx = fmaxf(fmaxf(c[0], c[1]), fmaxf(c[2], c[3]));
                #pragma unroll
                for (int msk = 1; msk < 16; msk <<= 1) {
                    mn = fminf(mn, __shfl_xor(mn, msk));
                    mx = fmaxf(mx, __shfl_xor(mx, msk));
                }
                int s = s_base + m * 16 + g * 4 + r;
                if (s < VQL) {
                    float scale = fmaxf((mx - mn) / 3.0f, 1e-8f);
                    float tol = 0.5f - 1e-3f / scale;
                    #pragma unroll
                    for (int n = 0; n < 4; ++n) {
                        float f = (c[n] - mn) / scale;
                        float qv = rintf(f);
                        if (fabsf(f - qv) > tol) {
                            int mg = row0 + wr * 64 + m * 16 + g * 4 + r;
                            int ng = col0 + wc * 64 + n * 16 + lr;
                            unsigned dst = 8388608u +
                                (unsigned)((((b * NHEAD + hcol) * 64) + n * 16 + lr) * SEQ + s);
                            push_flag(cnt, recs, dst, mg, ng, mn, scale);
                        }
                        acc[m][n][r] = qv * scale + mn;
                    }
                }
                // else raw unclipped tail (acc keeps bias-added value)
            }
        #pragma unroll
        for (int m = 0; m < 4; ++m)
            #pragma unroll
            for (int n = 0; n < 4; ++n) {
                ushort4_t o;
                #pragma unroll
                for (int r = 0; r < 4; ++r) o[r] = f2bf(acc[m][n][r]);
                *(ushort4_t*)(Vt + ((((size_t)b * NHEAD + hcol) * 64) + n * 16 + lr) * SEQ
                                 + s_base + m * 16 + g * 4) = o;
            }
    }
}

// ---------------------------------------------------------------------------
// Boundary repair: one wave per record; exact fp32 dot, requantize with the
// SAME group's mn/scale, rewrite the single bf16 element. Order-independent.
// ---------------------------------------------------------------------------
__global__ __launch_bounds__(256) void repair_kernel(
    const float* __restrict__ X,
    const unsigned short* __restrict__ WTh, const unsigned short* __restrict__ WTm,
    const unsigned short* __restrict__ WTl,
    const float* __restrict__ bias, unsigned short* __restrict__ wsu,
    const unsigned* __restrict__ cnt, const Rec* __restrict__ recs)
{
    const int lane = threadIdx.x & 63;
    const int wid  = blockIdx.x * 4 + (threadIdx.x >> 6);
    unsigned nrec = *cnt; if (nrec > REC_CAP) nrec = REC_CAP;
    for (unsigned i = wid; i < nrec; i += gridDim.x * 4) {
        Rec rc = recs[i];
        int mg = rc.mn_pack & 4095;
        int ng = (rc.mn_pack >> 12) & 4095;
        const float* xr          = X   + (size_t)mg * 1024 + lane * 16;
        const unsigned short* wh = WTh + (size_t)ng * 1024 + lane * 16;
        const unsigned short* wm = WTm + (size_t)ng * 1024 + lane * 16;
        const unsigned short* wl = WTl + (size_t)ng * 1024 + lane * 16;
        float s = 0.f;
        #pragma unroll
        for (int j4 = 0; j4 < 4; ++j4) {
            float4 xv = *(const float4*)(xr + j4 * 4);
            float xs[4] = {xv.x, xv.y, xv.z, xv.w};
            #pragma unroll
            for (int e = 0; e < 4; ++e) {
                int j = j4 * 4 + e;
                s += xs[e] * (bf2f(wh[j]) + bf2f(wm[j]) + bf2f(wl[j]));
            }
        }
        #pragma unroll
        for (int msk = 1; msk < 64; msk <<= 1) s += __shfl_xor(s, msk);
        if (lane == 0) {
            float v = clipf(s + bias[ng]);
            float val = rintf((v - rc.mn) / rc.scale) * rc.scale + rc.mn;
            wsu[rc.dst] = f2bf(val);
        }
    }
}

// ---------------------------------------------------------------------------
// MFMA flash attention (bf16, fp32 accum), causal, scale 1/8. (unchanged)
// ---------------------------------------------------------------------------
__global__ __launch_bounds__(256) void attn_mfma(
    unsigned short* __restrict__ QY,
    const unsigned short* __restrict__ K,
    const unsigned short* __restrict__ Vt)
{
    __shared__ unsigned short Ks [64][72];
    __shared__ unsigned short VsT[64][72];
    __shared__ unsigned short Ps [4][16][72];

    const int tid  = threadIdx.x;
    const int wave = tid >> 6;
    const int lane = tid & 63;
    const int lr   = lane & 15;
    const int g    = lane >> 4;

    const int bid = blockIdx.x;
    const int qt  = 31 - (bid >> 5);
    const int bh  = bid & 31;
    const size_t base = (size_t)bh * (SEQ * 64);

    const int qrow = qt * 64 + wave * 16 + lr;
    const unsigned short* qp = QY + base + (size_t)qrow * 64;
    bf16x8 aq[2];
    #pragma unroll
    for (int ka = 0; ka < 2; ++ka)
        aq[ka] = *(const bf16x8*)(qp + ka * 32 + g * 8);

    f32x4 o[4] = {};
    float m[4]    = {-1e30f, -1e30f, -1e30f, -1e30f};
    float lsum[4] = {};
    const float sc = 0.125f;

    const int str = tid >> 2;
    const int stc = (tid & 3) << 4;

    for (int jt = 0; jt <= qt; ++jt) {
        __syncthreads();
        {
            const unsigned short* kg = K + base + ((size_t)(jt * 64 + str) << 6) + stc;
            *(ushort8_t*)&Ks[str][stc]     = *(const ushort8_t*)kg;
            *(ushort8_t*)&Ks[str][stc + 8] = *(const ushort8_t*)(kg + 8);
            const unsigned short* vg = Vt + base + ((size_t)str << 11) + jt * 64 + stc;
            *(ushort8_t*)&VsT[str][stc]     = *(const ushort8_t*)vg;
            *(ushort8_t*)&VsT[str][stc + 8] = *(const ushort8_t*)(vg + 8);
        }
        __syncthreads();

        f32x4 s[4] = {};
        #pragma unroll
        for (int f = 0; f < 4; ++f) {
            #pragma unroll
            for (int ka = 0; ka < 2; ++ka) {
                bf16x8 bk = *(const bf16x8*)&Ks[f * 16 + lr][ka * 32 + g * 8];
                s[f] = __builtin_amdgcn_mfma_f32_16x16x32_bf16(aq[ka], bk, s[f], 0, 0, 0);
            }
        }

        const bool diag = (jt == qt);
        float mx[4];
        #pragma unroll
        for (int r = 0; r < 4; ++r) {
            const int ql = wave * 16 + g * 4 + r;
            float vmax = -1e30f;
            #pragma unroll
            for (int f = 0; f < 4; ++f) {
                float v = s[f][r] * sc;
                if (diag && (f * 16 + lr) > ql) v = -1e30f;
                s[f][r] = v;
                vmax = fmaxf(vmax, v);
            }
            mx[r] = vmax;
        }
        #pragma unroll
        for (int msk = 1; msk < 16; msk <<= 1)
            #pragma unroll
            for (int r = 0; r < 4; ++r)
                mx[r] = fmaxf(mx[r], __shfl_xor(mx[r], msk));

        float alpha[4], tsum[4];
        #pragma unroll
        for (int r = 0; r < 4; ++r) {
            float mn = fmaxf(m[r], mx[r]);
            alpha[r] = __expf(m[r] - mn);
            m[r] = mn;
            float ts = 0.0f;
            #pragma unroll
            for (int f = 0; f < 4; ++f) {
                float p = __expf(s[f][r] - mn);
                unsigned short ub = f2bf(p);
                Ps[wave][g * 4 + r][f * 16 + lr] = ub;
                ts += bf2f(ub);
            }
            tsum[r] = ts;
        }
        #pragma unroll
        for (int msk = 1; msk < 16; msk <<= 1)
            #pragma unroll
            for (int r = 0; r < 4; ++r)
                tsum[r] += __shfl_xor(tsum[r], msk);
        #pragma unroll
        for (int r = 0; r < 4; ++r) {
            lsum[r] = lsum[r] * alpha[r] + tsum[r];
            #pragma unroll
            for (int df = 0; df < 4; ++df) o[df][r] *= alpha[r];
        }

        asm volatile("s_waitcnt lgkmcnt(0)" ::: "memory");
        __builtin_amdgcn_sched_barrier(0);

        bf16x8 pa[2];
        #pragma unroll
        for (int kb = 0; kb < 2; ++kb)
            pa[kb] = *(const bf16x8*)&Ps[wave][lr][kb * 32 + g * 8];
        #pragma unroll
        for (int df = 0; df < 4; ++df) {
            #pragma unroll
            for (int kb = 0; kb < 2; ++kb) {
                bf16x8 vb = *(const bf16x8*)&VsT[df * 16 + lr][kb * 32 + g * 8];
                o[df] = __builtin_amdgcn_mfma_f32_16x16x32_bf16(pa[kb], vb, o[df], 0, 0, 0);
            }
        }
    }

    float invl[4];
    #pragma unroll
    for (int r = 0; r < 4; ++r) invl[r] = 1.0f / lsum[r];
    #pragma unroll
    for (int df = 0; df < 4; ++df)
        #pragma unroll
        for (int r = 0; r < 4; ++r) {
            int q = qt * 64 + wave * 16 + g * 4 + r;
            QY[base + (size_t)q * 64 + df * 16 + lr] = f2bf(o[df][r] * invl[r]);
        }
}

// ---------------------------------------------------------------------------
// Proj GEMM via bf16 MFMA (unchanged).
// ---------------------------------------------------------------------------
#define PJ_PAD 72
__global__ __launch_bounds__(256, 2) void gemm_proj_mfma(
    const unsigned short* __restrict__ Y, const float* __restrict__ W,
    const float* __restrict__ bias, float* __restrict__ C)
{
    __shared__ unsigned short A2[2][128][PJ_PAD];
    __shared__ unsigned short B2[2][128][PJ_PAD];

    const int tid  = threadIdx.x;
    const int wave = tid >> 6, lane = tid & 63, lr = lane & 15, g = lane >> 4;
    const int wr = wave >> 1, wc = wave & 1;
    const int row0 = blockIdx.y * 128, col0 = blockIdx.x * 128;
    const int b = row0 >> 11, s0 = row0 & 2047;

    const int ra  = tid >> 1,       ca  = (tid & 1) * 32;
    const int cb4 = (tid & 31) * 4, kb4 = (tid >> 5) * 4;

    ushort8_t a_reg[4];
    float bw[2][4][4];

    {
        const unsigned short* gy = Y + ((((size_t)b * NHEAD + 0) * SEQ + s0 + ra) << 6) + ca;
        #pragma unroll
        for (int i = 0; i < 4; ++i) a_reg[i] = *(const ushort8_t*)(gy + i * 8);
        const float* gw = W + (size_t)kb4 * EMB + col0 + cb4;
        #pragma unroll
        for (int half = 0; half < 2; ++half)
            #pragma unroll
            for (int i = 0; i < 4; ++i)
                *(float4*)bw[half][i] = *(const float4*)(gw + (size_t)(half * 32 + i) * EMB);
        #pragma unroll
        for (int i = 0; i < 4; ++i) *(ushort8_t*)&A2[0][ra][ca + i * 8] = a_reg[i];
        #pragma unroll
        for (int half = 0; half < 2; ++half)
            #pragma unroll
            for (int j = 0; j < 4; ++j) {
                unsigned w2[2];
                w2[0] = cvtpk(bw[half][0][j], bw[half][1][j]);
                w2[1] = cvtpk(bw[half][2][j], bw[half][3][j]);
                *(uint2_t*)&B2[0][cb4 + j][half * 32 + kb4] = *(uint2_t*)w2;
            }
    }
    __syncthreads();

    f32x4 acc[4][4] = {};

    for (int t = 0; t < 16; ++t) {
        const int cur = t & 1;
        if (t < 15) {
            const unsigned short* gy =
                Y + ((((size_t)b * NHEAD + (t + 1)) * SEQ + s0 + ra) << 6) + ca;
            #pragma unroll
            for (int i = 0; i < 4; ++i) a_reg[i] = *(const ushort8_t*)(gy + i * 8);
            const float* gw = W + (size_t)((t + 1) * 64 + kb4) * EMB + col0 + cb4;
            #pragma unroll
            for (int half = 0; half < 2; ++half)
                #pragma unroll
                for (int i = 0; i < 4; ++i)
                    *(float4*)bw[half][i] = *(const float4*)(gw + (size_t)(half * 32 + i) * EMB);
        }
        #pragma unroll
        for (int kk = 0; kk < 2; ++kk) {
            bf16x8 af[4];
            #pragma unroll
            for (int m = 0; m < 4; ++m)
                af[m] = *(const bf16x8*)&A2[cur][wr * 64 + m * 16 + lr][kk * 32 + g * 8];
            #pragma unroll
            for (int n = 0; n < 4; ++n) {
                bf16x8 bf = *(const bf16x8*)&B2[cur][wc * 64 + n * 16 + lr][kk * 32 + g * 8];
                #pragma unroll
                for (int m = 0; m < 4; ++m)
                    acc[m][n] = __builtin_amdgcn_mfma_f32_16x16x32_bf16(af[m], bf, acc[m][n], 0, 0, 0);
            }
        }
        if (t < 15) {
            const int nxt = cur ^ 1;
            #pragma unroll
            for (int i = 0; i < 4; ++i) *(ushort8_t*)&A2[nxt][ra][ca + i * 8] = a_reg[i];
            #pragma unroll
            for (int half = 0; half < 2; ++half)
                #pragma unroll
                for (int j = 0; j < 4; ++j) {
                    unsigned w2[2];
                    w2[0] = cvtpk(bw[half][0][j], bw[half][1][j]);
                    w2[1] = cvtpk(bw[half][2][j], bw[half][3][j]);
                    *(uint2_t*)&B2[nxt][cb4 + j][half * 32 + kb4] = *(uint2_t*)w2;
                }
        }
        __syncthreads();
    }

    float bo[4];
    #pragma unroll
    for (int n = 0; n < 4; ++n) bo[n] = bias[col0 + wc * 64 + n * 16 + lr];
    #pragma unroll
    for (int m = 0; m < 4; ++m)
        #pragma unroll
        for (int r = 0; r < 4; ++r) {
            int mrow = row0 + wr * 64 + m * 16 + g * 4 + r;
            #pragma unroll
            for (int n = 0; n < 4; ++n)
                C[(size_t)mrow * EMB + col0 + wc * 64 + n * 16 + lr] = acc[m][n][r] + bo[n];
        }
}

// ---------------------------------------------------------------------------
extern "C" void kernel_launch(void* const* d_in, const int* in_sizes, int n_in,
                              void* d_out, int out_size, void* d_ws, size_t ws_size,
                              hipStream_t stream)
{
    const float* x     = (const float*)d_in[0];
    const float* Wqkv  = (const float*)d_in[1];
    const float* bqkv  = (const float*)d_in[2];
    const float* Wproj = (const float*)d_in[3];
    const float* bproj = (const float*)d_in[4];
    float* out = (float*)d_out;

    // Workspace layout (~59.2 MiB total):
    //  [0,8)    MiB q bf16 [B,H,S,D] (y overwrites)
    //  [8,16)   MiB k bf16 [B,H,S,D]
    //  [16,24)  MiB v bf16 [B,H,D,S]
    //  [24,32)  MiB Xh   [32,40) Xm        bf16 [4096][1024]
    //  [40,46)  MiB WTh  [46,52) WTm  [52,58) WTl  bf16 [3072][1024]
    //  [58 MiB) counter + records
    char* ws = (char*)d_ws;
    unsigned short* q   = (unsigned short*)ws;
    unsigned short* kb  = (unsigned short*)(ws + (8u  << 20));
    unsigned short* vt  = (unsigned short*)(ws + (16u << 20));
    unsigned short* Xh  = (unsigned short*)(ws + (24u << 20));
    unsigned short* Xm  = (unsigned short*)(ws + (32u << 20));
    unsigned short* WTh = (unsigned short*)(ws + (40u << 20));
    unsigned short* WTm = (unsigned short*)(ws + (46u << 20));
    unsigned short* WTl = (unsigned short*)(ws + (52u << 20));
    unsigned*       cnt = (unsigned*)(ws + (58u << 20));
    Rec*           recs = (Rec*)(ws + (58u << 20) + 256);

    split_x_kernel<<<2048, 256, 0, stream>>>(x, Xh, Xm, cnt);
    split_wt_kernel<<<dim3(48, 16), 256, 0, stream>>>(Wqkv, WTh, WTm, WTl);
    gemm_qkv3<<<dim3(N3E / 128, 4096 / 128), 256, 0, stream>>>(
        Xh, Xm, WTh, WTm, bqkv, q, kb, vt, cnt, recs);
    repair_kernel<<<128, 256, 0, stream>>>(x, WTh, WTm, WTl, bqkv,
                                           (unsigned short*)d_ws, cnt, recs);
    attn_mfma<<<dim3(32 * 32), 256, 0, stream>>>(q, kb, vt);
    gemm_proj_mfma<<<dim3(EMB / 128, 4096 / 128), 256, 0, stream>>>(q, Wproj, bproj, out);
}